// Round 4
// baseline (5969.981 us; speedup 1.0000x reference)
//
#include <hip/hip_runtime.h>
#include <hip/hip_bf16.h>
#include <math.h>

typedef __hip_bfloat16 bf16;
typedef unsigned short ushort;
typedef __attribute__((ext_vector_type(8))) short bh8;
typedef __attribute__((ext_vector_type(4))) float f4;

#define HHW 48
#define PP  2304      // 48*48
#define MM  36864     // 16*2304

__device__ __forceinline__ float ldf(const float* p) { return *p; }
__device__ __forceinline__ float ldf(const bf16* p) { return __bfloat162float(*p); }
__device__ __forceinline__ void stf(float* p, float v) { *p = v; }
__device__ __forceinline__ void stf(bf16* p, float v) { *p = __float2bfloat16(v); }

// XOR-swizzled LDS offset (ushort units), stride 32/row, 4 slots of 8 ushorts.
// slot' = slot ^ ((row>>1)&3): verified conflict-free (SQ_LDS_BANK_CONFLICT=0, r3).
__device__ __forceinline__ int loff(int row, int col8) {
    return row * 32 + (col8 ^ ((((row) >> 1) & 3) << 3));
}

// ---------------- prep kernels ----------------
// x (16,1024,48,48) f32 NCHW -> xb (36864, 1024) bf16 NHWC, 32x32 LDS tile transpose
__global__ void x2b_k(const float* __restrict__ x, bf16* __restrict__ xb) {
    __shared__ float tile[32][33];
    int b  = blockIdx.z;
    int c0 = blockIdx.y * 32;
    int p0 = blockIdx.x * 32;
    int lp = threadIdx.x & 31;
    int cg = threadIdx.x >> 5;   // 0..7
    #pragma unroll
    for (int j = 0; j < 4; ++j) {
        int c = cg * 4 + j;
        tile[c][lp] = x[((size_t)b * 1024 + c0 + c) * PP + p0 + lp];
    }
    __syncthreads();
    #pragma unroll
    for (int j = 0; j < 4; ++j) {
        int rp = cg * 4 + j;
        xb[((size_t)b * PP + p0 + rp) * 1024 + c0 + lp] = __float2bfloat16(tile[lp][rp]);
    }
}

// w (Cout, Cin, 3, 3) f32 -> wb (9, Cout, Cin) bf16
__global__ void w3b_k(const float* __restrict__ w, bf16* __restrict__ wb, int Cout, int Cin) {
    int idx = blockIdx.x * 256 + threadIdx.x;
    int n = Cout * Cin * 9;
    if (idx >= n) return;
    int kk  = idx / (Cout * Cin);
    int rem = idx - kk * Cout * Cin;
    int co  = rem / Cin;
    int ci  = rem - co * Cin;
    wb[idx] = __float2bfloat16(w[((size_t)co * Cin + ci) * 9 + kk]);
}

// flat f32 -> bf16
__global__ void f2b_k(const float* __restrict__ s, bf16* __restrict__ d, int n) {
    int i = blockIdx.x * 256 + threadIdx.x;
    if (i < n) d[i] = __float2bfloat16(s[i]);
}

// w (O, C) f32 -> wt (C, O) f32  (for q/k/cls small GEMVs)
__global__ void tw1_k(const float* __restrict__ w, float* __restrict__ wt, int O, int Cm) {
    int idx = blockIdx.x * 256 + threadIdx.x;
    int n = O * Cm;
    if (idx >= n) return;
    int o = idx / Cm;
    int c = idx - o * Cm;
    wt[c * O + o] = w[idx];
}

// ---------------- MFMA implicit-GEMM 1x1 conv ----------------
// in: [36864, Cin] bf16 NHWC.  wt: [kcnt, Cout, CinT] bf16 (ci contiguous).
template<typename OutT>
__global__ __launch_bounds__(256, 2)
void mconv_k(const bf16* __restrict__ in, const bf16* __restrict__ wt,
             const float* __restrict__ bias, OutT* __restrict__ out,
             int Cin, int CinT, int ciOff, int Cout, int kcnt, int accum) {
    __shared__ ushort As[128 * 40];
    __shared__ ushort Bs[128 * 40];
    const ushort* inu = (const ushort*)in;
    const ushort* wtu = (const ushort*)wt;
    int tid = threadIdx.x;
    int N0 = blockIdx.x * 128;
    int M0 = blockIdx.y * 128;
    int sr = tid >> 2;
    int sc = (tid & 3) * 8;
    int p0 = M0 + sr, p1 = p0 + 64;
    int rr0 = p0 % PP, rr1 = p1 % PP;
    int y0 = rr0 / HHW, x0 = rr0 - y0 * HHW;
    int y1 = rr1 / HHW, x1 = rr1 - y1 * HHW;
    int wv = tid >> 6, lane = tid & 63;
    int wm = (wv & 1) * 64, wn = (wv >> 1) * 64;
    int l15 = lane & 15, quad = lane >> 4;

    f4 acc[4][4];
    #pragma unroll
    for (int i = 0; i < 4; ++i)
        #pragma unroll
        for (int j = 0; j < 4; ++j) acc[i][j] = (f4){0.f, 0.f, 0.f, 0.f};

    uint4 z4; z4.x = z4.y = z4.z = z4.w = 0;

    for (int k9 = 0; k9 < kcnt; ++k9) {
        int dy = (kcnt == 1) ? 0 : (k9 / 3 - 1);
        int dx = (kcnt == 1) ? 0 : (k9 % 3 - 1);
        bool v0 = ((unsigned)(y0 + dy) < (unsigned)HHW) && ((unsigned)(x0 + dx) < (unsigned)HHW);
        bool v1 = ((unsigned)(y1 + dy) < (unsigned)HHW) && ((unsigned)(x1 + dx) < (unsigned)HHW);
        const ushort* a0p = inu + (size_t)(p0 + dy * HHW + dx) * Cin + sc;
        const ushort* a1p = inu + (size_t)(p1 + dy * HHW + dx) * Cin + sc;
        const ushort* w0p = wtu + ((size_t)k9 * Cout + N0 + sr) * CinT + ciOff + sc;
        const ushort* w1p = w0p + (size_t)64 * CinT;
        for (int c0 = 0; c0 < Cin; c0 += 32) {
            __syncthreads();
            const uint4* pa0 = (const uint4*)(v0 ? (a0p + c0) : inu);
            const uint4* pa1 = (const uint4*)(v1 ? (a1p + c0) : inu);
            uint4 av0 = *pa0; if (!v0) av0 = z4;
            uint4 av1 = *pa1; if (!v1) av1 = z4;
            uint4 bv0 = *(const uint4*)(w0p + c0);
            uint4 bv1 = *(const uint4*)(w1p + c0);
            *(uint4*)(As + sr * 40 + sc) = av0;
            *(uint4*)(As + (sr + 64) * 40 + sc) = av1;
            *(uint4*)(Bs + sr * 40 + sc) = bv0;
            *(uint4*)(Bs + (sr + 64) * 40 + sc) = bv1;
            __syncthreads();
            bh8 af[4], bfr[4];
            #pragma unroll
            for (int mi = 0; mi < 4; ++mi)
                af[mi] = *(const bh8*)(As + (wm + mi * 16 + l15) * 40 + quad * 8);
            #pragma unroll
            for (int ni = 0; ni < 4; ++ni)
                bfr[ni] = *(const bh8*)(Bs + (wn + ni * 16 + l15) * 40 + quad * 8);
            #pragma unroll
            for (int mi = 0; mi < 4; ++mi)
                #pragma unroll
                for (int ni = 0; ni < 4; ++ni)
                    acc[mi][ni] = __builtin_amdgcn_mfma_f32_16x16x32_bf16(af[mi], bfr[ni], acc[mi][ni], 0, 0, 0);
        }
    }

    float bvn[4];
    #pragma unroll
    for (int ni = 0; ni < 4; ++ni)
        bvn[ni] = bias ? bias[N0 + wn + ni * 16 + l15] : 0.f;
    #pragma unroll
    for (int mi = 0; mi < 4; ++mi) {
        int mrow = M0 + wm + mi * 16 + quad * 4;
        #pragma unroll
        for (int ni = 0; ni < 4; ++ni) {
            int ncol = N0 + wn + ni * 16 + l15;
            #pragma unroll
            for (int r = 0; r < 4; ++r) {
                size_t oi = (size_t)(mrow + r) * Cout + ncol;
                float val = acc[mi][ni][r] + bvn[ni];
                if (accum) stf(&out[oi], ldf(&out[oi]) + val);
                else       stf(&out[oi], val);
            }
        }
    }
}

// ---------------- MFMA 3x3 conv, A-halo LDS reuse + reg-prefetch pipeline ----------------
// M-tile 96, grid 2x384/4x384, LDS 40 KB XOR-swizzled (conflicts=0, r3).
// T14 issue-early/write-late: staging loads go to REGISTERS one phase ahead
// (thread-private, so __syncthreads does NOT drain them, unlike global_load_lds);
// each phase writes prev-loaded regs to LDS then issues next phase's loads,
// giving them a full phase (~ds_reads+36 MFMA) of latency cover.
template<typename OutT>
__global__ __launch_bounds__(256, 2)
void mconv3_k(const bf16* __restrict__ in, const bf16* __restrict__ wt,
              const float* __restrict__ bias, OutT* __restrict__ out,
              int Cin, int CinT, int ciOff, int Cout, int accum) {
    __shared__ ushort As[256 * 32];   // halo rows M0-49..M0+206 (194 used)
    __shared__ ushort Bs[384 * 32];   // 3 taps x 128 cout rows
    const ushort* inu = (const ushort*)in;
    const ushort* wtu = (const ushort*)wt;
    int tid = threadIdx.x;
    int N0 = blockIdx.x * 128;
    int M0 = blockIdx.y * 96;
    int sr = tid >> 2;            // 0..63
    int sc = (tid & 3) * 8;       // 0,8,16,24
    int wv = tid >> 6, lane = tid & 63;
    int wm = (wv & 1) * 48, wn = (wv >> 1) * 64;
    int l15 = lane & 15, quad = lane >> 4;

    // A halo staging pointers (rows M0-49 .. M0+206, clamped; OOB masked at read)
    const ushort* aptr[4];
    #pragma unroll
    for (int j = 0; j < 4; ++j) {
        int gp = M0 - 49 + j * 64 + sr;
        gp = gp < 0 ? 0 : (gp > MM - 1 ? MM - 1 : gp);
        aptr[j] = inu + (size_t)gp * Cin + sc;
    }
    // B staging pointers for dy=0 taps; advance by dystep per dy
    const ushort* bptr[6];
    #pragma unroll
    for (int j = 0; j < 6; ++j) {
        int row = j * 64 + sr;            // 0..383
        int dxi = row >> 7;               // tap-within-dy 0..2
        int crow = row & 127;             // cout row within tile
        bptr[j] = wtu + ((size_t)dxi * Cout + N0 + crow) * CinT + ciOff + sc;
    }
    size_t dystep = (size_t)3 * Cout * CinT;

    // per-lane (y,x) of the 3 A-rows this lane feeds to MFMA (fixed)
    int ry[3], rx[3];
    #pragma unroll
    for (int mi = 0; mi < 3; ++mi) {
        int r = (M0 + wm + mi * 16 + l15) % PP;
        ry[mi] = r / HHW;
        rx[mi] = r - ry[mi] * HHW;
    }

    f4 acc[3][4];
    #pragma unroll
    for (int i = 0; i < 3; ++i)
        #pragma unroll
        for (int j = 0; j < 4; ++j) acc[i][j] = (f4){0.f, 0.f, 0.f, 0.f};

    // prologue prefetch: A(c0=0), B(c0=0, dy=0)
    uint4 areg[4], breg[6];
    #pragma unroll
    for (int j = 0; j < 4; ++j) areg[j] = *(const uint4*)(aptr[j]);
    #pragma unroll
    for (int j = 0; j < 6; ++j) breg[j] = *(const uint4*)(bptr[j]);

    for (int c0 = 0; c0 < Cin; c0 += 32) {
        #pragma unroll
        for (int dy = 0; dy < 3; ++dy) {
            __syncthreads();                       // prior-phase readers done
            if (dy == 0) {
                #pragma unroll
                for (int j = 0; j < 4; ++j)
                    *(uint4*)(As + loff(j * 64 + sr, sc)) = areg[j];
            }
            #pragma unroll
            for (int j = 0; j < 6; ++j)
                *(uint4*)(Bs + loff(j * 64 + sr, sc)) = breg[j];
            // issue next phase's staging loads (land before next phase's writes)
            if (dy < 2) {
                #pragma unroll
                for (int j = 0; j < 6; ++j)
                    breg[j] = *(const uint4*)(bptr[j] + (dy + 1) * dystep + c0);
            } else if (c0 + 32 < Cin) {
                #pragma unroll
                for (int j = 0; j < 6; ++j)
                    breg[j] = *(const uint4*)(bptr[j] + c0 + 32);
                #pragma unroll
                for (int j = 0; j < 4; ++j)
                    areg[j] = *(const uint4*)(aptr[j] + c0 + 32);
            }
            __syncthreads();
            int dyp = dy - 1;
            bool vy[3];
            #pragma unroll
            for (int mi = 0; mi < 3; ++mi) vy[mi] = (unsigned)(ry[mi] + dyp) < (unsigned)HHW;
            #pragma unroll
            for (int dxi = 0; dxi < 3; ++dxi) {
                int dxp = dxi - 1;
                int sh = 49 + dyp * HHW + dxp;     // LDS row shift for this tap
                bh8 af[3], bfr[4];
                #pragma unroll
                for (int mi = 0; mi < 3; ++mi) {
                    bh8 a = {0, 0, 0, 0, 0, 0, 0, 0};
                    if (vy[mi] && (unsigned)(rx[mi] + dxp) < (unsigned)HHW)
                        a = *(const bh8*)(As + loff(wm + mi * 16 + l15 + sh, quad * 8));
                    af[mi] = a;
                }
                #pragma unroll
                for (int ni = 0; ni < 4; ++ni)
                    bfr[ni] = *(const bh8*)(Bs + loff(dxi * 128 + wn + ni * 16 + l15, quad * 8));
                #pragma unroll
                for (int mi = 0; mi < 3; ++mi)
                    #pragma unroll
                    for (int ni = 0; ni < 4; ++ni)
                        acc[mi][ni] = __builtin_amdgcn_mfma_f32_16x16x32_bf16(af[mi], bfr[ni], acc[mi][ni], 0, 0, 0);
            }
        }
    }

    // epilogue: C/D layout col=lane&15, row=quad*4+reg  [m89-verified]
    float bvn[4];
    #pragma unroll
    for (int ni = 0; ni < 4; ++ni)
        bvn[ni] = bias ? bias[N0 + wn + ni * 16 + l15] : 0.f;
    #pragma unroll
    for (int mi = 0; mi < 3; ++mi) {
        int mrow = M0 + wm + mi * 16 + quad * 4;
        #pragma unroll
        for (int ni = 0; ni < 4; ++ni) {
            int ncol = N0 + wn + ni * 16 + l15;
            #pragma unroll
            for (int r = 0; r < 4; ++r) {
                size_t oi = (size_t)(mrow + r) * Cout + ncol;
                float val = acc[mi][ni][r] + bvn[ni];
                if (accum) stf(&out[oi], ldf(&out[oi]) + val);
                else       stf(&out[oi], val);
            }
        }
    }
}

// ---------------- batch norm ----------------
__global__ void zero_k(float* p, int n) {
    int i = blockIdx.x * 256 + threadIdx.x;
    if (i < n) p[i] = 0.f;
}

template<typename S>
__global__ void bn_stats_k(const S* __restrict__ src, float* __restrict__ sum,
                           float* __restrict__ sumsq, int Cout) {
    int t  = threadIdx.x;
    int c  = blockIdx.x * 64 + (t & 63);
    int pl = t >> 6;
    int p0 = blockIdx.y * 1024;
    float s = 0.f, ss = 0.f;
    for (int i = pl; i < 1024; i += 4) {
        float v = ldf(&src[(size_t)(p0 + i) * Cout + c]);
        s += v; ss += v * v;
    }
    __shared__ float ls[256], lss[256];
    ls[t] = s; lss[t] = ss;
    __syncthreads();
    if (t < 64) {
        s  = ls[t]  + ls[t + 64]  + ls[t + 128]  + ls[t + 192];
        ss = lss[t] + lss[t + 64] + lss[t + 128] + lss[t + 192];
        atomicAdd(&sum[c], s);
        atomicAdd(&sumsq[c], ss);
    }
}

__global__ void bn_fin_k(const float* __restrict__ sum, const float* __restrict__ sumsq,
                         const float* __restrict__ g, const float* __restrict__ b,
                         float* __restrict__ scale, float* __restrict__ shift, int Cout) {
    int c = blockIdx.x * 256 + threadIdx.x;
    if (c >= Cout) return;
    const float invM = 1.f / 36864.f;
    float mean = sum[c] * invM;
    float var  = sumsq[c] * invM - mean * mean;
    float inv  = 1.f / sqrtf(var + 1e-5f);
    scale[c] = g[c] * inv;
    shift[c] = b[c] - mean * g[c] * inv;
}

template<typename S, typename D>
__global__ void bn_apply_k(const S* __restrict__ src, const float* __restrict__ scale,
                           const float* __restrict__ shift, D* __restrict__ dst,
                           int cmask, int n) {
    int idx = blockIdx.x * 256 + threadIdx.x;
    if (idx >= n) return;
    int c = idx & cmask;
    float y = ldf(&src[idx]) * scale[c] + shift[c];
    stf(&dst[idx], fmaxf(y, 0.f));
}

// ---------------- conv1x1 q/k (bf16 in, f32 wt (C,O), f32 out) ----------------
__global__ void conv1x1_k(const bf16* __restrict__ in, const float* __restrict__ wt,
                          const float* __restrict__ bias, float* __restrict__ out,
                          int Cc, int O) {
    int o = threadIdx.x;                       // 32
    int p = blockIdx.x * blockDim.y + threadIdx.y;
    const bf16* ib = in + (size_t)p * Cc;
    float acc = 0.f;
    #pragma unroll 4
    for (int c = 0; c < Cc; ++c) acc += __bfloat162float(ib[c]) * wt[c * O + o];
    out[(size_t)p * O + o] = acc + bias[o];
}

// ---------------- criss-cross spatial attention ----------------
__global__ void cc_logits_k(const float* __restrict__ q, const float* __restrict__ kk,
                            float* __restrict__ att) {
    int t = threadIdx.x;
    int p = blockIdx.x;
    int b = p / PP;
    int r = p - b * PP;
    int h = r / HHW;
    int w = r - h * HHW;
    __shared__ float qv[32];
    if (t < 32) qv[t] = q[p * 32 + t];
    __syncthreads();
    float val = -INFINITY;
    if (t < 48) {
        if (t != h) {
            const float* kr = kk + ((b * HHW + t) * HHW + w) * 32;
            float s = 0.f;
            #pragma unroll
            for (int c = 0; c < 32; ++c) s += qv[c] * kr[c];
            val = s;
        }
    } else if (t < 96) {
        const float* kr = kk + ((b * HHW + h) * HHW + (t - 48)) * 32;
        float s = 0.f;
        #pragma unroll
        for (int c = 0; c < 32; ++c) s += qv[c] * kr[c];
        val = s;
    }
    __shared__ float red[128];
    red[t] = val;
    __syncthreads();
    for (int st = 64; st > 0; st >>= 1) { if (t < st) red[t] = fmaxf(red[t], red[t + st]); __syncthreads(); }
    float m = red[0];
    __syncthreads();
    float e = (t < 96 && val != -INFINITY) ? expf(val - m) : 0.f;
    red[t] = e;
    __syncthreads();
    for (int st = 64; st > 0; st >>= 1) { if (t < st) red[t] += red[t + st]; __syncthreads(); }
    float inv = 1.f / red[0];
    if (t < 96) att[p * 96 + t] = e * inv;
}

// block 256 (= channel) per pixel; in-place bf16 residual update of cc
__global__ void cc_out_k(const float* __restrict__ att, const float* __restrict__ v,
                         bf16* __restrict__ cc, const float* __restrict__ gptr) {
    int t = threadIdx.x;
    int p = blockIdx.x;
    __shared__ float a[96];
    if (t < 96) a[t] = att[p * 96 + t];
    __syncthreads();
    int b = p / PP;
    int r = p - b * PP;
    int h = r / HHW;
    int w = r - h * HHW;
    const float* vb = v + (size_t)b * PP * 256;
    float acc = 0.f;
    #pragma unroll 4
    for (int g = 0; g < 48; ++g)   acc += a[g]      * vb[(g * HHW + w) * 256 + t];
    #pragma unroll 4
    for (int tt = 0; tt < 48; ++tt) acc += a[48 + tt] * vb[(h * HHW + tt) * 256 + t];
    float gamma = gptr[0];
    size_t oi = (size_t)p * 256 + t;
    cc[oi] = __float2bfloat16(gamma * acc + __bfloat162float(cc[oi]));
}

// ---------------- batch-grid ("my") attention ----------------
__global__ void gram_k(const float* __restrict__ q, const float* __restrict__ k,
                       float* __restrict__ G) {
    int t = threadIdx.x;
    int a  = blockIdx.x >> 4;
    int b2 = blockIdx.x & 15;
    const float* qa = q + a * 73728;
    const float* kb = k + b2 * 73728;
    float s = 0.f;
    for (int i = t; i < 73728; i += 256) s += qa[i] * kb[i];
    __shared__ float red[256];
    red[t] = s;
    __syncthreads();
    for (int st = 128; st > 0; st >>= 1) { if (t < st) red[t] += red[t + st]; __syncthreads(); }
    if (t == 0) G[blockIdx.x] = red[0];
}

__global__ void my_soft_k(const float* __restrict__ G, float* __restrict__ A) {
    int t = threadIdx.x;
    if (t >= 16) return;
    int i = t >> 2, j = t & 3;
    float l[8];
    for (int g = 0; g < 4; ++g) l[g] = (g == i) ? -INFINITY : G[t * 16 + g * 4 + j];
    for (int v = 0; v < 4; ++v) l[4 + v] = G[t * 16 + i * 4 + v];
    float m = l[0];
    for (int n = 1; n < 8; ++n) m = fmaxf(m, l[n]);
    float s = 0.f;
    for (int n = 0; n < 8; ++n) { l[n] = expf(l[n] - m); s += l[n]; }
    float inv = 1.f / s;
    for (int n = 0; n < 8; ++n) A[t * 8 + n] = l[n] * inv;
}

__global__ void my_out_k(const float* __restrict__ A, const float* __restrict__ v,
                         bf16* __restrict__ my, const float* __restrict__ gptr) {
    int t = threadIdx.x;
    __shared__ float As[128];
    if (t < 128) As[t] = A[t];
    __syncthreads();
    int idx = blockIdx.x * 256 + t;
    int b = idx / 589824;
    int n = idx - b * 589824;
    int i = b >> 2, j = b & 3;
    float o = 0.f;
    for (int g = 0; g < 4; ++g)   o += As[b * 8 + g]      * v[(g * 4 + j) * 589824 + n];
    for (int tt = 0; tt < 4; ++tt) o += As[b * 8 + 4 + tt] * v[(i * 4 + tt) * 589824 + n];
    float gamma = gptr[0];
    my[idx] = __float2bfloat16(gamma * o + __bfloat162float(my[idx]));
}

// ---------------- classifier 1x1 -> f32 NCHW ----------------
__global__ void cls_k(const float* __restrict__ hsrc, const float* __restrict__ wt,
                      const float* __restrict__ bias, float* __restrict__ out) {
    int t = threadIdx.x;      // 128
    int p = blockIdx.x;
    __shared__ float hr[512];
    for (int i = t; i < 512; i += 128) hr[i] = hsrc[(size_t)p * 512 + i];
    __syncthreads();
    if (t < 21) {
        float acc = bias[t];
        #pragma unroll 4
        for (int c = 0; c < 512; ++c) acc += hr[c] * wt[c * 21 + t];
        int b = p / PP;
        int r = p - b * PP;
        out[(b * 21 + t) * PP + r] = acc;
    }
}

// ---------------- launch ----------------
extern "C" void kernel_launch(void* const* d_in, const int* in_sizes, int n_in,
                              void* d_out, int out_size, void* d_ws, size_t ws_size,
                              hipStream_t stream) {
    const float* x     = (const float*)d_in[0];
    const float* w_a   = (const float*)d_in[1];
    const float* g_a   = (const float*)d_in[2];
    const float* b_a   = (const float*)d_in[3];
    const float* ccq_w = (const float*)d_in[4];
    const float* ccq_b = (const float*)d_in[5];
    const float* cck_w = (const float*)d_in[6];
    const float* cck_b = (const float*)d_in[7];
    const float* ccv_w = (const float*)d_in[8];
    const float* ccv_b = (const float*)d_in[9];
    const float* cc_g  = (const float*)d_in[10];
    const float* w_b   = (const float*)d_in[11];
    const float* g_b   = (const float*)d_in[12];
    const float* b_b   = (const float*)d_in[13];
    const float* w_m1  = (const float*)d_in[14];
    const float* g_m1  = (const float*)d_in[15];
    const float* b_m1  = (const float*)d_in[16];
    const float* myq_w = (const float*)d_in[17];
    const float* myq_b = (const float*)d_in[18];
    const float* myk_w = (const float*)d_in[19];
    const float* myk_b = (const float*)d_in[20];
    const float* myv_w = (const float*)d_in[21];
    const float* myv_b = (const float*)d_in[22];
    const float* my_g  = (const float*)d_in[23];
    const float* w_m2  = (const float*)d_in[24];
    const float* g_m2  = (const float*)d_in[25];
    const float* b_m2  = (const float*)d_in[26];
    const float* w_c   = (const float*)d_in[27];
    const float* g_c   = (const float*)d_in[28];
    const float* b_c   = (const float*)d_in[29];
    const float* w_cls = (const float*)d_in[30];
    const float* b_cls = (const float*)d_in[31];
    float* out = (float*)d_out;

    char* ws = (char*)d_ws;
    size_t off = 0;
    bf16* cc  = (bf16*)(ws + off); off += (size_t)MM * 256 * 2;     // 18,874,368
    bf16* my  = (bf16*)(ws + off); off += (size_t)MM * 256 * 2;
    char* hx  = ws + off;          off += (size_t)MM * 256 * 4;     // 37,748,736 (f32 256 OR bf16 512)
    char* B   = ws + off;          off += (size_t)MM * 512 * 4;     // 75,497,472 multi-use
    bf16* wab  = (bf16*)(ws + off); off += 4718592;
    bf16* wm1b = (bf16*)(ws + off); off += 4718592;
    bf16* wbb  = (bf16*)(ws + off); off += 1179648;
    bf16* wm2b = (bf16*)(ws + off); off += 1179648;
    bf16* wcb  = (bf16*)(ws + off); off += 14155776;
    bf16* wvcb = (bf16*)(ws + off); off += 131072;
    bf16* wvmb = (bf16*)(ws + off); off += 131072;
    float* ccqT = (float*)(ws + off); off += 32768;
    float* cckT = (float*)(ws + off); off += 32768;
    float* myqT = (float*)(ws + off); off += 32768;
    float* mykT = (float*)(ws + off); off += 32768;
    float* wclsT = (float*)(ws + off); off += 43008;
    float* stats = (float*)(ws + off); off += 16384;
    if (ws_size < off) return;   // ~177.4 MB
    float* ssum   = stats;
    float* ssumsq = stats + 512;
    float* sscale = stats + 1024;
    float* sshift = stats + 1536;
    float* G = stats + 2048;
    float* A = stats + 2048 + 256;

    // region B sub-views
    bf16*  xbf = (bf16*)B;                           // [36864,1024] early
    float* qb  = (float*)B;                          // attention phase
    float* kb  = (float*)(B + 4718592);
    float* vb  = (float*)(B + 9437184);              // [36864,256] f32
    float* att = (float*)(B + 47185920);             // [36864,96]  f32
    float* hxf = (float*)hx;                         // conv scratch f32 [36864,256]
    bf16*  hxb = (bf16*)hx;                          // concat accum bf16 [36864,512]
    float* hfin = (float*)B;                         // final BN output f32 [36864,512]

    // ---- prep ----
    x2b_k<<<dim3(72, 32, 16), 256, 0, stream>>>(x, xbf);
    w3b_k<<<9216, 256, 0, stream>>>(w_a,  wab,  256, 1024);
    w3b_k<<<9216, 256, 0, stream>>>(w_m1, wm1b, 256, 1024);
    w3b_k<<<2304, 256, 0, stream>>>(w_b,  wbb,  256, 256);
    w3b_k<<<2304, 256, 0, stream>>>(w_m2, wm2b, 256, 256);
    w3b_k<<<27648, 256, 0, stream>>>(w_c, wcb,  512, 1536);
    f2b_k<<<256, 256, 0, stream>>>(ccv_w, wvcb, 65536);
    f2b_k<<<256, 256, 0, stream>>>(myv_w, wvmb, 65536);
    tw1_k<<<32, 256, 0, stream>>>(ccq_w, ccqT, 32, 256);
    tw1_k<<<32, 256, 0, stream>>>(cck_w, cckT, 32, 256);
    tw1_k<<<32, 256, 0, stream>>>(myq_w, myqT, 32, 256);
    tw1_k<<<32, 256, 0, stream>>>(myk_w, mykT, 32, 256);
    tw1_k<<<42, 256, 0, stream>>>(w_cls, wclsT, 21, 512);

    auto bn = [&](auto* src, const float* g, const float* b, auto* dst, int Cout) {
        zero_k<<<4, 256, 0, stream>>>(ssum, 1024);
        bn_stats_k<<<dim3(Cout / 64, 36), 256, 0, stream>>>(src, ssum, ssumsq, Cout);
        bn_fin_k<<<(Cout + 255) / 256, 256, 0, stream>>>(ssum, ssumsq, g, b, sscale, sshift, Cout);
        int n = MM * Cout;
        bn_apply_k<<<n / 256, 256, 0, stream>>>(src, sscale, sshift, dst, Cout - 1, n);
    };

    // ---- initial convs (read xbf in B) ----
    mconv3_k<float><<<dim3(2, 384), 256, 0, stream>>>(xbf, wab, nullptr, hxf, 1024, 1024, 0, 256, 0);
    bn(hxf, g_a, b_a, cc, 256);
    mconv3_k<float><<<dim3(2, 384), 256, 0, stream>>>(xbf, wm1b, nullptr, hxf, 1024, 1024, 0, 256, 0);
    bn(hxf, g_m1, b_m1, my, 256);
    // concat x-part now (before B is reused): -> hx as bf16 [36864,512]
    mconv3_k<bf16><<<dim3(4, 384), 256, 0, stream>>>(xbf, wcb, nullptr, hxb, 1024, 1536, 0, 512, 0);

    // ---- criss-cross spatial attention x2 (bf16 cc in-place) ----
    for (int rec = 0; rec < 2; ++rec) {
        conv1x1_k<<<dim3(MM / 8), dim3(32, 8), 0, stream>>>(cc, ccqT, ccq_b, qb, 256, 32);
        conv1x1_k<<<dim3(MM / 8), dim3(32, 8), 0, stream>>>(cc, cckT, cck_b, kb, 256, 32);
        mconv_k<float><<<dim3(2, 288), 256, 0, stream>>>(cc, wvcb, ccv_b, vb, 256, 256, 0, 256, 1, 0);
        cc_logits_k<<<MM, 128, 0, stream>>>(qb, kb, att);
        cc_out_k<<<MM, 256, 0, stream>>>(att, vb, cc, cc_g);
    }

    // ---- batch-grid attention x2 (bf16 my in-place) ----
    for (int rec = 0; rec < 2; ++rec) {
        conv1x1_k<<<dim3(MM / 8), dim3(32, 8), 0, stream>>>(my, myqT, myq_b, qb, 256, 32);
        conv1x1_k<<<dim3(MM / 8), dim3(32, 8), 0, stream>>>(my, mykT, myk_b, kb, 256, 32);
        mconv_k<float><<<dim3(2, 288), 256, 0, stream>>>(my, wvmb, myv_b, vb, 256, 256, 0, 256, 1, 0);
        gram_k<<<256, 256, 0, stream>>>(qb, kb, G);
        my_soft_k<<<1, 64, 0, stream>>>(G, A);
        my_out_k<<<MM, 256, 0, stream>>>(A, vb, my, my_g);
    }

    // ---- post convs (outputs -> B as f32 scratch; B attention data dead) ----
    float* pscr = (float*)B;
    mconv3_k<float><<<dim3(2, 384), 256, 0, stream>>>(cc, wbb, nullptr, pscr, 256, 256, 0, 256, 0);
    bn(pscr, g_b, b_b, cc, 256);
    mconv3_k<float><<<dim3(2, 384), 256, 0, stream>>>(my, wm2b, nullptr, pscr, 256, 256, 0, 256, 0);
    bn(pscr, g_m2, b_m2, my, 256);

    // ---- concat cc/my parts accumulate into hxb ----
    mconv3_k<bf16><<<dim3(4, 384), 256, 0, stream>>>(cc, wcb, nullptr, hxb, 256, 1536, 1024, 512, 1);
    mconv3_k<bf16><<<dim3(4, 384), 256, 0, stream>>>(my, wcb, nullptr, hxb, 256, 1536, 1280, 512, 1);
    bn(hxb, g_c, b_c, hfin, 512);

    // ---- classifier ----
    cls_k<<<MM, 128, 0, stream>>>(hfin, wclsT, b_cls, out);
}

// Round 5
// 3558.020 us; speedup vs baseline: 1.6779x; 1.6779x over previous
//
#include <hip/hip_runtime.h>
#include <hip/hip_bf16.h>
#include <math.h>

typedef __hip_bfloat16 bf16;
typedef unsigned short ushort;
typedef __attribute__((ext_vector_type(8))) short bh8;
typedef __attribute__((ext_vector_type(4))) float f4;

#define HHW 48
#define PP  2304      // 48*48
#define MM  36864     // 16*2304

__device__ __forceinline__ float ldf(const float* p) { return *p; }
__device__ __forceinline__ float ldf(const bf16* p) { return __bfloat162float(*p); }
__device__ __forceinline__ void stf(float* p, float v) { *p = v; }
__device__ __forceinline__ void stf(bf16* p, float v) { *p = __float2bfloat16(v); }

// XOR swizzle: slot' = slot ^ ((row>>1)&3).  Verified conflict-free (r3: SQ_LDS_BANK_CONFLICT=0).
// Applied on READ via loff(); on WRITE via pre-swizzled GLOBAL source address
// (global_load_lds writes LDS linearly: wave-uniform base + lane*16B; m104/m173).
__device__ __forceinline__ int loff(int row, int col8) {
    return row * 32 + (col8 ^ ((((row) >> 1) & 3) << 3));
}

// async global->LDS DMA, 16B per lane. gptr is PER-LANE, lptr must be wave-uniform.
__device__ __forceinline__ void gl_lds(const ushort* g, ushort* l) {
    __builtin_amdgcn_global_load_lds((const __attribute__((address_space(1))) void*)g,
                                     (__attribute__((address_space(3))) void*)l, 16, 0, 0);
}

// ---------------- prep kernels ----------------
// x (16,1024,48,48) f32 NCHW -> xb (36864, 1024) bf16 NHWC, 32x32 LDS tile transpose
__global__ void x2b_k(const float* __restrict__ x, bf16* __restrict__ xb) {
    __shared__ float tile[32][33];
    int b  = blockIdx.z;
    int c0 = blockIdx.y * 32;
    int p0 = blockIdx.x * 32;
    int lp = threadIdx.x & 31;
    int cg = threadIdx.x >> 5;   // 0..7
    #pragma unroll
    for (int j = 0; j < 4; ++j) {
        int c = cg * 4 + j;
        tile[c][lp] = x[((size_t)b * 1024 + c0 + c) * PP + p0 + lp];
    }
    __syncthreads();
    #pragma unroll
    for (int j = 0; j < 4; ++j) {
        int rp = cg * 4 + j;
        xb[((size_t)b * PP + p0 + rp) * 1024 + c0 + lp] = __float2bfloat16(tile[lp][rp]);
    }
}

// w (Cout, Cin, 3, 3) f32 -> wb (9, Cout, Cin) bf16
__global__ void w3b_k(const float* __restrict__ w, bf16* __restrict__ wb, int Cout, int Cin) {
    int idx = blockIdx.x * 256 + threadIdx.x;
    int n = Cout * Cin * 9;
    if (idx >= n) return;
    int kk  = idx / (Cout * Cin);
    int rem = idx - kk * Cout * Cin;
    int co  = rem / Cin;
    int ci  = rem - co * Cin;
    wb[idx] = __float2bfloat16(w[((size_t)co * Cin + ci) * 9 + kk]);
}

// flat f32 -> bf16
__global__ void f2b_k(const float* __restrict__ s, bf16* __restrict__ d, int n) {
    int i = blockIdx.x * 256 + threadIdx.x;
    if (i < n) d[i] = __float2bfloat16(s[i]);
}

// w (O, C) f32 -> wt (C, O) f32  (for q/k/cls small GEMVs)
__global__ void tw1_k(const float* __restrict__ w, float* __restrict__ wt, int O, int Cm) {
    int idx = blockIdx.x * 256 + threadIdx.x;
    int n = O * Cm;
    if (idx >= n) return;
    int o = idx / Cm;
    int c = idx - o * Cm;
    wt[c * O + o] = w[idx];
}

// ---------------- MFMA implicit-GEMM 1x1 conv ----------------
// in: [36864, Cin] bf16 NHWC.  wt: [kcnt, Cout, CinT] bf16 (ci contiguous).
template<typename OutT>
__global__ __launch_bounds__(256, 2)
void mconv_k(const bf16* __restrict__ in, const bf16* __restrict__ wt,
             const float* __restrict__ bias, OutT* __restrict__ out,
             int Cin, int CinT, int ciOff, int Cout, int kcnt, int accum) {
    __shared__ ushort As[128 * 40];
    __shared__ ushort Bs[128 * 40];
    const ushort* inu = (const ushort*)in;
    const ushort* wtu = (const ushort*)wt;
    int tid = threadIdx.x;
    int N0 = blockIdx.x * 128;
    int M0 = blockIdx.y * 128;
    int sr = tid >> 2;
    int sc = (tid & 3) * 8;
    int p0 = M0 + sr, p1 = p0 + 64;
    int rr0 = p0 % PP, rr1 = p1 % PP;
    int y0 = rr0 / HHW, x0 = rr0 - y0 * HHW;
    int y1 = rr1 / HHW, x1 = rr1 - y1 * HHW;
    int wv = tid >> 6, lane = tid & 63;
    int wm = (wv & 1) * 64, wn = (wv >> 1) * 64;
    int l15 = lane & 15, quad = lane >> 4;

    f4 acc[4][4];
    #pragma unroll
    for (int i = 0; i < 4; ++i)
        #pragma unroll
        for (int j = 0; j < 4; ++j) acc[i][j] = (f4){0.f, 0.f, 0.f, 0.f};

    uint4 z4; z4.x = z4.y = z4.z = z4.w = 0;

    for (int k9 = 0; k9 < kcnt; ++k9) {
        int dy = (kcnt == 1) ? 0 : (k9 / 3 - 1);
        int dx = (kcnt == 1) ? 0 : (k9 % 3 - 1);
        bool v0 = ((unsigned)(y0 + dy) < (unsigned)HHW) && ((unsigned)(x0 + dx) < (unsigned)HHW);
        bool v1 = ((unsigned)(y1 + dy) < (unsigned)HHW) && ((unsigned)(x1 + dx) < (unsigned)HHW);
        const ushort* a0p = inu + (size_t)(p0 + dy * HHW + dx) * Cin + sc;
        const ushort* a1p = inu + (size_t)(p1 + dy * HHW + dx) * Cin + sc;
        const ushort* w0p = wtu + ((size_t)k9 * Cout + N0 + sr) * CinT + ciOff + sc;
        const ushort* w1p = w0p + (size_t)64 * CinT;
        for (int c0 = 0; c0 < Cin; c0 += 32) {
            __syncthreads();
            const uint4* pa0 = (const uint4*)(v0 ? (a0p + c0) : inu);
            const uint4* pa1 = (const uint4*)(v1 ? (a1p + c0) : inu);
            uint4 av0 = *pa0; if (!v0) av0 = z4;
            uint4 av1 = *pa1; if (!v1) av1 = z4;
            uint4 bv0 = *(const uint4*)(w0p + c0);
            uint4 bv1 = *(const uint4*)(w1p + c0);
            *(uint4*)(As + sr * 40 + sc) = av0;
            *(uint4*)(As + (sr + 64) * 40 + sc) = av1;
            *(uint4*)(Bs + sr * 40 + sc) = bv0;
            *(uint4*)(Bs + (sr + 64) * 40 + sc) = bv1;
            __syncthreads();
            bh8 af[4], bfr[4];
            #pragma unroll
            for (int mi = 0; mi < 4; ++mi)
                af[mi] = *(const bh8*)(As + (wm + mi * 16 + l15) * 40 + quad * 8);
            #pragma unroll
            for (int ni = 0; ni < 4; ++ni)
                bfr[ni] = *(const bh8*)(Bs + (wn + ni * 16 + l15) * 40 + quad * 8);
            #pragma unroll
            for (int mi = 0; mi < 4; ++mi)
                #pragma unroll
                for (int ni = 0; ni < 4; ++ni)
                    acc[mi][ni] = __builtin_amdgcn_mfma_f32_16x16x32_bf16(af[mi], bfr[ni], acc[mi][ni], 0, 0, 0);
        }
    }

    float bvn[4];
    #pragma unroll
    for (int ni = 0; ni < 4; ++ni)
        bvn[ni] = bias ? bias[N0 + wn + ni * 16 + l15] : 0.f;
    #pragma unroll
    for (int mi = 0; mi < 4; ++mi) {
        int mrow = M0 + wm + mi * 16 + quad * 4;
        #pragma unroll
        for (int ni = 0; ni < 4; ++ni) {
            int ncol = N0 + wn + ni * 16 + l15;
            #pragma unroll
            for (int r = 0; r < 4; ++r) {
                size_t oi = (size_t)(mrow + r) * Cout + ncol;
                float val = acc[mi][ni][r] + bvn[ni];
                if (accum) stf(&out[oi], ldf(&out[oi]) + val);
                else       stf(&out[oi], val);
            }
        }
    }
}

// ---------------- MFMA 3x3 conv, A-halo LDS reuse + global_load_lds staging ----------------
// M-tile 96, grid 2x384/4x384, LDS 40 KB, 3 blocks/CU resident (cap 4), no tail.
// r3 structure (553us, conflicts=0) with staging switched from reg round-trip to
// global_load_lds DMA (m151: +35% vs reg-staging at this structure; m193: width16 +67%).
// No registers live across barriers -> nothing to spill (r2/r4 lesson).
// Store pattern (row=tid>>2-derived, slot=tid&3) is exactly lane-linear per
// (segment,wave): one DMA instr per segment, wave-uniform LDS base + lane*16B.
// XOR swizzle moved to the per-lane GLOBAL source address; reads use loff() unchanged.
template<typename OutT>
__global__ __launch_bounds__(256, 2)
void mconv3_k(const bf16* __restrict__ in, const bf16* __restrict__ wt,
              const float* __restrict__ bias, OutT* __restrict__ out,
              int Cin, int CinT, int ciOff, int Cout, int accum) {
    __shared__ ushort As[256 * 32];   // halo rows M0-49..M0+206 (194 used)
    __shared__ ushort Bs[384 * 32];   // 3 taps x 128 cout rows
    const ushort* inu = (const ushort*)in;
    const ushort* wtu = (const ushort*)wt;
    int tid = threadIdx.x;
    int N0 = blockIdx.x * 128;
    int M0 = blockIdx.y * 96;
    int sr = tid >> 2;            // 0..63 (LDS row within segment)
    int sc = (tid & 3) * 8;       // 0,8,16,24 (linear LDS slot)
    int wv = tid >> 6, lane = tid & 63;
    int wm = (wv & 1) * 48, wn = (wv >> 1) * 64;
    int l15 = lane & 15, quad = lane >> 4;

    // A staging: per-lane pre-swizzled global src, wave-uniform linear LDS dest
    const ushort* aptr[4];
    ushort* alds[4];
    #pragma unroll
    for (int j = 0; j < 4; ++j) {
        int row = j * 64 + sr;                         // LDS row
        int scs = sc ^ (((row >> 1) & 3) << 3);        // pre-swizzled col slot
        int gp = M0 - 49 + row;                        // global pixel row (clamped)
        gp = gp < 0 ? 0 : (gp > MM - 1 ? MM - 1 : gp);
        aptr[j] = inu + (size_t)gp * Cin + scs;
        alds[j] = As + (j * 64 + wv * 16) * 32;        // wave-uniform base
    }
    // B staging pointers for dy=0 taps; advance by dystep per dy
    const ushort* bptr[6];
    ushort* blds[6];
    #pragma unroll
    for (int j = 0; j < 6; ++j) {
        int row = j * 64 + sr;            // 0..383
        int scs = sc ^ (((row >> 1) & 3) << 3);
        int dxi = row >> 7;               // tap-within-dy 0..2
        int crow = row & 127;             // cout row within tile
        bptr[j] = wtu + ((size_t)dxi * Cout + N0 + crow) * CinT + ciOff + scs;
        blds[j] = Bs + (j * 64 + wv * 16) * 32;
    }
    size_t dystep = (size_t)3 * Cout * CinT;

    // per-lane (y,x) of the 3 A-rows this lane feeds to MFMA (fixed)
    int ry[3], rx[3];
    #pragma unroll
    for (int mi = 0; mi < 3; ++mi) {
        int r = (M0 + wm + mi * 16 + l15) % PP;
        ry[mi] = r / HHW;
        rx[mi] = r - ry[mi] * HHW;
    }

    f4 acc[3][4];
    #pragma unroll
    for (int i = 0; i < 3; ++i)
        #pragma unroll
        for (int j = 0; j < 4; ++j) acc[i][j] = (f4){0.f, 0.f, 0.f, 0.f};

    for (int c0 = 0; c0 < Cin; c0 += 32) {
        #pragma unroll
        for (int dy = 0; dy < 3; ++dy) {
            __syncthreads();                       // prior-phase readers done
            if (dy == 0) {
                #pragma unroll
                for (int j = 0; j < 4; ++j)
                    gl_lds(aptr[j] + c0, alds[j]);
            }
            #pragma unroll
            for (int j = 0; j < 6; ++j)
                gl_lds(bptr[j] + dy * dystep + c0, blds[j]);
            __syncthreads();                       // drains vmcnt -> LDS visible
            int dyp = dy - 1;
            bool vy[3];
            #pragma unroll
            for (int mi = 0; mi < 3; ++mi) vy[mi] = (unsigned)(ry[mi] + dyp) < (unsigned)HHW;
            #pragma unroll
            for (int dxi = 0; dxi < 3; ++dxi) {
                int dxp = dxi - 1;
                int sh = 49 + dyp * HHW + dxp;     // LDS row shift for this tap
                bh8 af[3], bfr[4];
                #pragma unroll
                for (int mi = 0; mi < 3; ++mi) {
                    bh8 a = {0, 0, 0, 0, 0, 0, 0, 0};
                    if (vy[mi] && (unsigned)(rx[mi] + dxp) < (unsigned)HHW)
                        a = *(const bh8*)(As + loff(wm + mi * 16 + l15 + sh, quad * 8));
                    af[mi] = a;
                }
                #pragma unroll
                for (int ni = 0; ni < 4; ++ni)
                    bfr[ni] = *(const bh8*)(Bs + loff(dxi * 128 + wn + ni * 16 + l15, quad * 8));
                #pragma unroll
                for (int mi = 0; mi < 3; ++mi)
                    #pragma unroll
                    for (int ni = 0; ni < 4; ++ni)
                        acc[mi][ni] = __builtin_amdgcn_mfma_f32_16x16x32_bf16(af[mi], bfr[ni], acc[mi][ni], 0, 0, 0);
            }
        }
    }

    // epilogue: C/D layout col=lane&15, row=quad*4+reg  [m89-verified]
    float bvn[4];
    #pragma unroll
    for (int ni = 0; ni < 4; ++ni)
        bvn[ni] = bias ? bias[N0 + wn + ni * 16 + l15] : 0.f;
    #pragma unroll
    for (int mi = 0; mi < 3; ++mi) {
        int mrow = M0 + wm + mi * 16 + quad * 4;
        #pragma unroll
        for (int ni = 0; ni < 4; ++ni) {
            int ncol = N0 + wn + ni * 16 + l15;
            #pragma unroll
            for (int r = 0; r < 4; ++r) {
                size_t oi = (size_t)(mrow + r) * Cout + ncol;
                float val = acc[mi][ni][r] + bvn[ni];
                if (accum) stf(&out[oi], ldf(&out[oi]) + val);
                else       stf(&out[oi], val);
            }
        }
    }
}

// ---------------- batch norm ----------------
__global__ void zero_k(float* p, int n) {
    int i = blockIdx.x * 256 + threadIdx.x;
    if (i < n) p[i] = 0.f;
}

template<typename S>
__global__ void bn_stats_k(const S* __restrict__ src, float* __restrict__ sum,
                           float* __restrict__ sumsq, int Cout) {
    int t  = threadIdx.x;
    int c  = blockIdx.x * 64 + (t & 63);
    int pl = t >> 6;
    int p0 = blockIdx.y * 1024;
    float s = 0.f, ss = 0.f;
    for (int i = pl; i < 1024; i += 4) {
        float v = ldf(&src[(size_t)(p0 + i) * Cout + c]);
        s += v; ss += v * v;
    }
    __shared__ float ls[256], lss[256];
    ls[t] = s; lss[t] = ss;
    __syncthreads();
    if (t < 64) {
        s  = ls[t]  + ls[t + 64]  + ls[t + 128]  + ls[t + 192];
        ss = lss[t] + lss[t + 64] + lss[t + 128] + lss[t + 192];
        atomicAdd(&sum[c], s);
        atomicAdd(&sumsq[c], ss);
    }
}

__global__ void bn_fin_k(const float* __restrict__ sum, const float* __restrict__ sumsq,
                         const float* __restrict__ g, const float* __restrict__ b,
                         float* __restrict__ scale, float* __restrict__ shift, int Cout) {
    int c = blockIdx.x * 256 + threadIdx.x;
    if (c >= Cout) return;
    const float invM = 1.f / 36864.f;
    float mean = sum[c] * invM;
    float var  = sumsq[c] * invM - mean * mean;
    float inv  = 1.f / sqrtf(var + 1e-5f);
    scale[c] = g[c] * inv;
    shift[c] = b[c] - mean * g[c] * inv;
}

template<typename S, typename D>
__global__ void bn_apply_k(const S* __restrict__ src, const float* __restrict__ scale,
                           const float* __restrict__ shift, D* __restrict__ dst,
                           int cmask, int n) {
    int idx = blockIdx.x * 256 + threadIdx.x;
    if (idx >= n) return;
    int c = idx & cmask;
    float y = ldf(&src[idx]) * scale[c] + shift[c];
    stf(&dst[idx], fmaxf(y, 0.f));
}

// ---------------- conv1x1 q/k (bf16 in, f32 wt (C,O), f32 out) ----------------
__global__ void conv1x1_k(const bf16* __restrict__ in, const float* __restrict__ wt,
                          const float* __restrict__ bias, float* __restrict__ out,
                          int Cc, int O) {
    int o = threadIdx.x;                       // 32
    int p = blockIdx.x * blockDim.y + threadIdx.y;
    const bf16* ib = in + (size_t)p * Cc;
    float acc = 0.f;
    #pragma unroll 4
    for (int c = 0; c < Cc; ++c) acc += __bfloat162float(ib[c]) * wt[c * O + o];
    out[(size_t)p * O + o] = acc + bias[o];
}

// ---------------- criss-cross spatial attention ----------------
__global__ void cc_logits_k(const float* __restrict__ q, const float* __restrict__ kk,
                            float* __restrict__ att) {
    int t = threadIdx.x;
    int p = blockIdx.x;
    int b = p / PP;
    int r = p - b * PP;
    int h = r / HHW;
    int w = r - h * HHW;
    __shared__ float qv[32];
    if (t < 32) qv[t] = q[p * 32 + t];
    __syncthreads();
    float val = -INFINITY;
    if (t < 48) {
        if (t != h) {
            const float* kr = kk + ((b * HHW + t) * HHW + w) * 32;
            float s = 0.f;
            #pragma unroll
            for (int c = 0; c < 32; ++c) s += qv[c] * kr[c];
            val = s;
        }
    } else if (t < 96) {
        const float* kr = kk + ((b * HHW + h) * HHW + (t - 48)) * 32;
        float s = 0.f;
        #pragma unroll
        for (int c = 0; c < 32; ++c) s += qv[c] * kr[c];
        val = s;
    }
    __shared__ float red[128];
    red[t] = val;
    __syncthreads();
    for (int st = 64; st > 0; st >>= 1) { if (t < st) red[t] = fmaxf(red[t], red[t + st]); __syncthreads(); }
    float m = red[0];
    __syncthreads();
    float e = (t < 96 && val != -INFINITY) ? expf(val - m) : 0.f;
    red[t] = e;
    __syncthreads();
    for (int st = 64; st > 0; st >>= 1) { if (t < st) red[t] += red[t + st]; __syncthreads(); }
    float inv = 1.f / red[0];
    if (t < 96) att[p * 96 + t] = e * inv;
}

// block 256 (= channel) per pixel; in-place bf16 residual update of cc
__global__ void cc_out_k(const float* __restrict__ att, const float* __restrict__ v,
                         bf16* __restrict__ cc, const float* __restrict__ gptr) {
    int t = threadIdx.x;
    int p = blockIdx.x;
    __shared__ float a[96];
    if (t < 96) a[t] = att[p * 96 + t];
    __syncthreads();
    int b = p / PP;
    int r = p - b * PP;
    int h = r / HHW;
    int w = r - h * HHW;
    const float* vb = v + (size_t)b * PP * 256;
    float acc = 0.f;
    #pragma unroll 4
    for (int g = 0; g < 48; ++g)   acc += a[g]      * vb[(g * HHW + w) * 256 + t];
    #pragma unroll 4
    for (int tt = 0; tt < 48; ++tt) acc += a[48 + tt] * vb[(h * HHW + tt) * 256 + t];
    float gamma = gptr[0];
    size_t oi = (size_t)p * 256 + t;
    cc[oi] = __float2bfloat16(gamma * acc + __bfloat162float(cc[oi]));
}

// ---------------- batch-grid ("my") attention ----------------
__global__ void gram_k(const float* __restrict__ q, const float* __restrict__ k,
                       float* __restrict__ G) {
    int t = threadIdx.x;
    int a  = blockIdx.x >> 4;
    int b2 = blockIdx.x & 15;
    const float* qa = q + a * 73728;
    const float* kb = k + b2 * 73728;
    float s = 0.f;
    for (int i = t; i < 73728; i += 256) s += qa[i] * kb[i];
    __shared__ float red[256];
    red[t] = s;
    __syncthreads();
    for (int st = 128; st > 0; st >>= 1) { if (t < st) red[t] += red[t + st]; __syncthreads(); }
    if (t == 0) G[blockIdx.x] = red[0];
}

__global__ void my_soft_k(const float* __restrict__ G, float* __restrict__ A) {
    int t = threadIdx.x;
    if (t >= 16) return;
    int i = t >> 2, j = t & 3;
    float l[8];
    for (int g = 0; g < 4; ++g) l[g] = (g == i) ? -INFINITY : G[t * 16 + g * 4 + j];
    for (int v = 0; v < 4; ++v) l[4 + v] = G[t * 16 + i * 4 + v];
    float m = l[0];
    for (int n = 1; n < 8; ++n) m = fmaxf(m, l[n]);
    float s = 0.f;
    for (int n = 0; n < 8; ++n) { l[n] = expf(l[n] - m); s += l[n]; }
    float inv = 1.f / s;
    for (int n = 0; n < 8; ++n) A[t * 8 + n] = l[n] * inv;
}

__global__ void my_out_k(const float* __restrict__ A, const float* __restrict__ v,
                         bf16* __restrict__ my, const float* __restrict__ gptr) {
    int t = threadIdx.x;
    __shared__ float As[128];
    if (t < 128) As[t] = A[t];
    __syncthreads();
    int idx = blockIdx.x * 256 + t;
    int b = idx / 589824;
    int n = idx - b * 589824;
    int i = b >> 2, j = b & 3;
    float o = 0.f;
    for (int g = 0; g < 4; ++g)   o += As[b * 8 + g]      * v[(g * 4 + j) * 589824 + n];
    for (int tt = 0; tt < 4; ++tt) o += As[b * 8 + 4 + tt] * v[(i * 4 + tt) * 589824 + n];
    float gamma = gptr[0];
    my[idx] = __float2bfloat16(gamma * o + __bfloat162float(my[idx]));
}

// ---------------- classifier 1x1 -> f32 NCHW ----------------
__global__ void cls_k(const float* __restrict__ hsrc, const float* __restrict__ wt,
                      const float* __restrict__ bias, float* __restrict__ out) {
    int t = threadIdx.x;      // 128
    int p = blockIdx.x;
    __shared__ float hr[512];
    for (int i = t; i < 512; i += 128) hr[i] = hsrc[(size_t)p * 512 + i];
    __syncthreads();
    if (t < 21) {
        float acc = bias[t];
        #pragma unroll 4
        for (int c = 0; c < 512; ++c) acc += hr[c] * wt[c * 21 + t];
        int b = p / PP;
        int r = p - b * PP;
        out[(b * 21 + t) * PP + r] = acc;
    }
}

// ---------------- launch ----------------
extern "C" void kernel_launch(void* const* d_in, const int* in_sizes, int n_in,
                              void* d_out, int out_size, void* d_ws, size_t ws_size,
                              hipStream_t stream) {
    const float* x     = (const float*)d_in[0];
    const float* w_a   = (const float*)d_in[1];
    const float* g_a   = (const float*)d_in[2];
    const float* b_a   = (const float*)d_in[3];
    const float* ccq_w = (const float*)d_in[4];
    const float* ccq_b = (const float*)d_in[5];
    const float* cck_w = (const float*)d_in[6];
    const float* cck_b = (const float*)d_in[7];
    const float* ccv_w = (const float*)d_in[8];
    const float* ccv_b = (const float*)d_in[9];
    const float* cc_g  = (const float*)d_in[10];
    const float* w_b   = (const float*)d_in[11];
    const float* g_b   = (const float*)d_in[12];
    const float* b_b   = (const float*)d_in[13];
    const float* w_m1  = (const float*)d_in[14];
    const float* g_m1  = (const float*)d_in[15];
    const float* b_m1  = (const float*)d_in[16];
    const float* myq_w = (const float*)d_in[17];
    const float* myq_b = (const float*)d_in[18];
    const float* myk_w = (const float*)d_in[19];
    const float* myk_b = (const float*)d_in[20];
    const float* myv_w = (const float*)d_in[21];
    const float* myv_b = (const float*)d_in[22];
    const float* my_g  = (const float*)d_in[23];
    const float* w_m2  = (const float*)d_in[24];
    const float* g_m2  = (const float*)d_in[25];
    const float* b_m2  = (const float*)d_in[26];
    const float* w_c   = (const float*)d_in[27];
    const float* g_c   = (const float*)d_in[28];
    const float* b_c   = (const float*)d_in[29];
    const float* w_cls = (const float*)d_in[30];
    const float* b_cls = (const float*)d_in[31];
    float* out = (float*)d_out;

    char* ws = (char*)d_ws;
    size_t off = 0;
    bf16* cc  = (bf16*)(ws + off); off += (size_t)MM * 256 * 2;     // 18,874,368
    bf16* my  = (bf16*)(ws + off); off += (size_t)MM * 256 * 2;
    char* hx  = ws + off;          off += (size_t)MM * 256 * 4;     // 37,748,736 (f32 256 OR bf16 512)
    char* B   = ws + off;          off += (size_t)MM * 512 * 4;     // 75,497,472 multi-use
    bf16* wab  = (bf16*)(ws + off); off += 4718592;
    bf16* wm1b = (bf16*)(ws + off); off += 4718592;
    bf16* wbb  = (bf16*)(ws + off); off += 1179648;
    bf16* wm2b = (bf16*)(ws + off); off += 1179648;
    bf16* wcb  = (bf16*)(ws + off); off += 14155776;
    bf16* wvcb = (bf16*)(ws + off); off += 131072;
    bf16* wvmb = (bf16*)(ws + off); off += 131072;
    float* ccqT = (float*)(ws + off); off += 32768;
    float* cckT = (float*)(ws + off); off += 32768;
    float* myqT = (float*)(ws + off); off += 32768;
    float* mykT = (float*)(ws + off); off += 32768;
    float* wclsT = (float*)(ws + off); off += 43008;
    float* stats = (float*)(ws + off); off += 16384;
    if (ws_size < off) return;   // ~177.4 MB
    float* ssum   = stats;
    float* ssumsq = stats + 512;
    float* sscale = stats + 1024;
    float* sshift = stats + 1536;
    float* G = stats + 2048;
    float* A = stats + 2048 + 256;

    // region B sub-views
    bf16*  xbf = (bf16*)B;                           // [36864,1024] early
    float* qb  = (float*)B;                          // attention phase
    float* kb  = (float*)(B + 4718592);
    float* vb  = (float*)(B + 9437184);              // [36864,256] f32
    float* att = (float*)(B + 47185920);             // [36864,96]  f32
    float* hxf = (float*)hx;                         // conv scratch f32 [36864,256]
    bf16*  hxb = (bf16*)hx;                          // concat accum bf16 [36864,512]
    float* hfin = (float*)B;                         // final BN output f32 [36864,512]

    // ---- prep ----
    x2b_k<<<dim3(72, 32, 16), 256, 0, stream>>>(x, xbf);
    w3b_k<<<9216, 256, 0, stream>>>(w_a,  wab,  256, 1024);
    w3b_k<<<9216, 256, 0, stream>>>(w_m1, wm1b, 256, 1024);
    w3b_k<<<2304, 256, 0, stream>>>(w_b,  wbb,  256, 256);
    w3b_k<<<2304, 256, 0, stream>>>(w_m2, wm2b, 256, 256);
    w3b_k<<<27648, 256, 0, stream>>>(w_c, wcb,  512, 1536);
    f2b_k<<<256, 256, 0, stream>>>(ccv_w, wvcb, 65536);
    f2b_k<<<256, 256, 0, stream>>>(myv_w, wvmb, 65536);
    tw1_k<<<32, 256, 0, stream>>>(ccq_w, ccqT, 32, 256);
    tw1_k<<<32, 256, 0, stream>>>(cck_w, cckT, 32, 256);
    tw1_k<<<32, 256, 0, stream>>>(myq_w, myqT, 32, 256);
    tw1_k<<<32, 256, 0, stream>>>(myk_w, mykT, 32, 256);
    tw1_k<<<42, 256, 0, stream>>>(w_cls, wclsT, 21, 512);

    auto bn = [&](auto* src, const float* g, const float* b, auto* dst, int Cout) {
        zero_k<<<4, 256, 0, stream>>>(ssum, 1024);
        bn_stats_k<<<dim3(Cout / 64, 36), 256, 0, stream>>>(src, ssum, ssumsq, Cout);
        bn_fin_k<<<(Cout + 255) / 256, 256, 0, stream>>>(ssum, ssumsq, g, b, sscale, sshift, Cout);
        int n = MM * Cout;
        bn_apply_k<<<n / 256, 256, 0, stream>>>(src, sscale, sshift, dst, Cout - 1, n);
    };

    // ---- initial convs (read xbf in B) ----
    mconv3_k<float><<<dim3(2, 384), 256, 0, stream>>>(xbf, wab, nullptr, hxf, 1024, 1024, 0, 256, 0);
    bn(hxf, g_a, b_a, cc, 256);
    mconv3_k<float><<<dim3(2, 384), 256, 0, stream>>>(xbf, wm1b, nullptr, hxf, 1024, 1024, 0, 256, 0);
    bn(hxf, g_m1, b_m1, my, 256);
    // concat x-part now (before B is reused): -> hx as bf16 [36864,512]
    mconv3_k<bf16><<<dim3(4, 384), 256, 0, stream>>>(xbf, wcb, nullptr, hxb, 1024, 1536, 0, 512, 0);

    // ---- criss-cross spatial attention x2 (bf16 cc in-place) ----
    for (int rec = 0; rec < 2; ++rec) {
        conv1x1_k<<<dim3(MM / 8), dim3(32, 8), 0, stream>>>(cc, ccqT, ccq_b, qb, 256, 32);
        conv1x1_k<<<dim3(MM / 8), dim3(32, 8), 0, stream>>>(cc, cckT, cck_b, kb, 256, 32);
        mconv_k<float><<<dim3(2, 288), 256, 0, stream>>>(cc, wvcb, ccv_b, vb, 256, 256, 0, 256, 1, 0);
        cc_logits_k<<<MM, 128, 0, stream>>>(qb, kb, att);
        cc_out_k<<<MM, 256, 0, stream>>>(att, vb, cc, cc_g);
    }

    // ---- batch-grid attention x2 (bf16 my in-place) ----
    for (int rec = 0; rec < 2; ++rec) {
        conv1x1_k<<<dim3(MM / 8), dim3(32, 8), 0, stream>>>(my, myqT, myq_b, qb, 256, 32);
        conv1x1_k<<<dim3(MM / 8), dim3(32, 8), 0, stream>>>(my, mykT, myk_b, kb, 256, 32);
        mconv_k<float><<<dim3(2, 288), 256, 0, stream>>>(my, wvmb, myv_b, vb, 256, 256, 0, 256, 1, 0);
        gram_k<<<256, 256, 0, stream>>>(qb, kb, G);
        my_soft_k<<<1, 64, 0, stream>>>(G, A);
        my_out_k<<<MM, 256, 0, stream>>>(A, vb, my, my_g);
    }

    // ---- post convs (outputs -> B as f32 scratch; B attention data dead) ----
    float* pscr = (float*)B;
    mconv3_k<float><<<dim3(2, 384), 256, 0, stream>>>(cc, wbb, nullptr, pscr, 256, 256, 0, 256, 0);
    bn(pscr, g_b, b_b, cc, 256);
    mconv3_k<float><<<dim3(2, 384), 256, 0, stream>>>(my, wm2b, nullptr, pscr, 256, 256, 0, 256, 0);
    bn(pscr, g_m2, b_m2, my, 256);

    // ---- concat cc/my parts accumulate into hxb ----
    mconv3_k<bf16><<<dim3(4, 384), 256, 0, stream>>>(cc, wcb, nullptr, hxb, 256, 1536, 1024, 512, 1);
    mconv3_k<bf16><<<dim3(4, 384), 256, 0, stream>>>(my, wcb, nullptr, hxb, 256, 1536, 1280, 512, 1);
    bn(hxb, g_c, b_c, hfin, 512);

    // ---- classifier ----
    cls_k<<<MM, 128, 0, stream>>>(hfin, wclsT, b_cls, out);
}